// Round 1
// baseline (1170.291 us; speedup 1.0000x reference)
//
#include <hip/hip_runtime.h>

#define NDIM 128

// ---- degree accumulation (float counts; exact up to 2^24) ----
__global__ __launch_bounds__(256) void deg_kernel(const int* __restrict__ senders,
                                                  const int* __restrict__ receivers,
                                                  float* __restrict__ degs,
                                                  float* __restrict__ degr, int ne)
{
    int e = blockIdx.x * 256 + threadIdx.x;
    if (e < ne) {
        atomicAdd(&degs[senders[e]], 1.0f);
        atomicAdd(&degr[receivers[e]], 1.0f);
    }
}

// ---- in-place deg -> rsqrt(max(deg,1)) ----
__global__ __launch_bounds__(256) void rsqrt_kernel(float* __restrict__ deg, int n)
{
    int i = blockIdx.x * 256 + threadIdx.x;
    if (i < n) deg[i] = rsqrtf(fmaxf(deg[i], 1.0f));
}

// ---- h = (nodes @ W + b) * inv_sqrt_sender_deg ----
// Block: 256 threads = 8 rows x 32 col-groups (4 cols each). W staged in LDS (64 KiB).
__global__ __launch_bounds__(256) void gemm_kernel(const float* __restrict__ nodes,
                                                   const float* __restrict__ W,
                                                   const float* __restrict__ b,
                                                   const float* __restrict__ inv_s,
                                                   float* __restrict__ h, int n)
{
    __shared__ __align__(16) float4 Wl[NDIM * 32];   // W[k][d4], 64 KiB
    __shared__ __align__(16) float  nl[8][NDIM];     // 4 KiB node rows
    __shared__ __align__(16) float  bl[NDIM];

    const float4* W4 = (const float4*)W;
    for (int i = threadIdx.x; i < NDIM * 32; i += 256) Wl[i] = W4[i];
    if (threadIdx.x < NDIM) bl[threadIdx.x] = b[threadIdx.x];

    int row0 = blockIdx.x * 8;
    {
        int t  = threadIdx.x;
        int rr = t >> 5, c4 = t & 31;
        int row = row0 + rr;
        float4 v = make_float4(0.f, 0.f, 0.f, 0.f);
        if (row < n) v = *(const float4*)(nodes + (size_t)row * NDIM + c4 * 4);
        *(float4*)(&nl[rr][c4 * 4]) = v;
    }
    __syncthreads();

    int ty = threadIdx.x >> 5;   // row within block
    int tx = threadIdx.x & 31;   // col group of 4
    int row = row0 + ty;
    if (row >= n) return;

    float4 acc = *(const float4*)(&bl[tx * 4]);
    #pragma unroll 8
    for (int k = 0; k < NDIM; ++k) {
        float  nv = nl[ty][k];          // broadcast within wave half
        float4 w  = Wl[k * 32 + tx];    // stride-16B, conflict-free
        acc.x = fmaf(nv, w.x, acc.x);
        acc.y = fmaf(nv, w.y, acc.y);
        acc.z = fmaf(nv, w.z, acc.z);
        acc.w = fmaf(nv, w.w, acc.w);
    }
    float is = inv_s[row];
    acc.x *= is; acc.y *= is; acc.z *= is; acc.w *= is;
    *(float4*)(h + (size_t)row * NDIM + tx * 4) = acc;
}

// ---- edge scatter: out[r] += h[s], 32 threads/edge, 4 floats/thread ----
__global__ __launch_bounds__(256) void scatter_kernel(const float* __restrict__ h,
                                                      const int* __restrict__ senders,
                                                      const int* __restrict__ receivers,
                                                      float* __restrict__ out, int ne)
{
    int gid = blockIdx.x * 256 + threadIdx.x;
    int e = gid >> 5;
    if (e >= ne) return;
    int q = (gid & 31) * 4;
    int s = senders[e];
    int r = receivers[e];
    float4 v = *(const float4*)(h + (size_t)s * NDIM + q);
    float* o = out + (size_t)r * NDIM + q;
    atomicAdd(o + 0, v.x);
    atomicAdd(o + 1, v.y);
    atomicAdd(o + 2, v.z);
    atomicAdd(o + 3, v.w);
}

// ---- out[i] *= inv_sqrt_receiver_deg[i] ----
__global__ __launch_bounds__(256) void scale_kernel(float* __restrict__ out,
                                                    const float* __restrict__ inv_r, int n)
{
    int gid = blockIdx.x * 256 + threadIdx.x;
    int row = gid >> 5;
    if (row >= n) return;
    int q = (gid & 31) * 4;
    float4 v = *(float4*)(out + (size_t)row * NDIM + q);
    float ir = inv_r[row];
    v.x *= ir; v.y *= ir; v.z *= ir; v.w *= ir;
    *(float4*)(out + (size_t)row * NDIM + q) = v;
}

extern "C" void kernel_launch(void* const* d_in, const int* in_sizes, int n_in,
                              void* d_out, int out_size, void* d_ws, size_t ws_size,
                              hipStream_t stream)
{
    const float* nodes     = (const float*)d_in[0];
    const int*   senders   = (const int*)d_in[1];
    const int*   receivers = (const int*)d_in[2];
    const float* W         = (const float*)d_in[3];
    const float* b         = (const float*)d_in[4];
    float*       out       = (float*)d_out;

    int n  = in_sizes[0] / NDIM;   // 50000
    int ne = in_sizes[1];          // 600000

    // ws layout: [deg_s (n) | deg_r (n) | pad | h (n*128)]
    float* degs = (float*)d_ws;
    float* degr = degs + n;
    size_t h_off = (((size_t)2 * n * sizeof(float)) + 255) & ~(size_t)255;
    float* h = (float*)((char*)d_ws + h_off);

    hipMemsetAsync(degs, 0, (size_t)2 * n * sizeof(float), stream);
    hipMemsetAsync(out, 0, (size_t)n * NDIM * sizeof(float), stream);

    deg_kernel<<<(ne + 255) / 256, 256, 0, stream>>>(senders, receivers, degs, degr, ne);
    rsqrt_kernel<<<(2 * n + 255) / 256, 256, 0, stream>>>(degs, 2 * n);
    gemm_kernel<<<(n + 7) / 8, 256, 0, stream>>>(nodes, W, b, degs, h, n);

    int scat_blocks = (int)(((long long)ne * 32 + 255) / 256);
    scatter_kernel<<<scat_blocks, 256, 0, stream>>>(h, senders, receivers, out, ne);
    scale_kernel<<<(n * 32 + 255) / 256, 256, 0, stream>>>(out, degr, n);
}

// Round 2
// 263.464 us; speedup vs baseline: 4.4419x; 4.4419x over previous
//
#include <hip/hip_runtime.h>

#define NDIM 128

// ---- int degree histogram ----
__global__ __launch_bounds__(256) void deg_kernel(const int* __restrict__ senders,
                                                  const int* __restrict__ receivers,
                                                  int* __restrict__ degs_i,
                                                  int* __restrict__ degr_i, int ne)
{
    int e = blockIdx.x * 256 + threadIdx.x;
    if (e < ne) {
        atomicAdd(&degs_i[senders[e]], 1);
        atomicAdd(&degr_i[receivers[e]], 1);
    }
}

// ---- inv_s / inv_r = rsqrt(max(deg,1)) ----
__global__ __launch_bounds__(256) void invdeg_kernel(const int* __restrict__ degs_i,
                                                     const int* __restrict__ degr_i,
                                                     float* __restrict__ inv_s,
                                                     float* __restrict__ inv_r, int n)
{
    int i = blockIdx.x * 256 + threadIdx.x;
    if (i < n) {
        inv_s[i] = rsqrtf(fmaxf((float)degs_i[i], 1.0f));
        inv_r[i] = rsqrtf(fmaxf((float)degr_i[i], 1.0f));
    }
}

// ---- scan phase A: per-block (256) reduce of degr_i -> partials ----
__global__ __launch_bounds__(256) void scanA_kernel(const int* __restrict__ degr_i,
                                                    int* __restrict__ partials, int n)
{
    __shared__ int s[256];
    int t = threadIdx.x;
    int i = blockIdx.x * 256 + t;
    s[t] = (i < n) ? degr_i[i] : 0;
    __syncthreads();
    for (int o = 128; o > 0; o >>= 1) {
        if (t < o) s[t] += s[t + o];
        __syncthreads();
    }
    if (t == 0) partials[blockIdx.x] = s[0];
}

// ---- scan phase B: single-block exclusive scan of partials (nb <= 256) ----
__global__ __launch_bounds__(256) void scanB_kernel(int* __restrict__ partials, int nb)
{
    __shared__ int s[256];
    int t = threadIdx.x;
    int v = (t < nb) ? partials[t] : 0;
    s[t] = v;
    __syncthreads();
    for (int o = 1; o < 256; o <<= 1) {
        int add = (t >= o) ? s[t - o] : 0;
        __syncthreads();
        s[t] += add;
        __syncthreads();
    }
    if (t < nb) partials[t] = s[t] - v;   // exclusive
}

// ---- scan phase C: per-block exclusive scan + block offset -> offsets, cursor ----
__global__ __launch_bounds__(256) void scanC_kernel(const int* __restrict__ degr_i,
                                                    const int* __restrict__ partials,
                                                    int* __restrict__ offsets,
                                                    int* __restrict__ cursor, int n)
{
    __shared__ int s[256];
    int t = threadIdx.x;
    int i = blockIdx.x * 256 + t;
    int v = (i < n) ? degr_i[i] : 0;
    s[t] = v;
    __syncthreads();
    for (int o = 1; o < 256; o <<= 1) {
        int add = (t >= o) ? s[t - o] : 0;
        __syncthreads();
        s[t] += add;
        __syncthreads();
    }
    if (i < n) {
        int off = partials[blockIdx.x] + s[t] - v;
        offsets[i] = off;
        cursor[i]  = off;
    }
}

// ---- bucket fill: csr_src[pos in receiver bucket] = sender ----
__global__ __launch_bounds__(256) void fill_kernel(const int* __restrict__ senders,
                                                   const int* __restrict__ receivers,
                                                   int* __restrict__ cursor,
                                                   int* __restrict__ csr_src, int ne)
{
    int e = blockIdx.x * 256 + threadIdx.x;
    if (e < ne) {
        int r = receivers[e];
        int pos = atomicAdd(&cursor[r], 1);
        csr_src[pos] = senders[e];
    }
}

// ---- wave-per-node gather-accumulate (no atomics) ----
// out_row[r] = inv_r[r] * sum_e inv_s[s_e] * nodes[s_e];  swb[r] = inv_r[r] * sum_e inv_s[s_e]
__global__ __launch_bounds__(256) void gather_kernel(const float* __restrict__ nodes,
                                                     const int* __restrict__ csr_src,
                                                     const int* __restrict__ offsets,
                                                     const int* __restrict__ degr_i,
                                                     const float* __restrict__ inv_s,
                                                     const float* __restrict__ inv_r,
                                                     float* __restrict__ out,
                                                     float* __restrict__ swb, int n)
{
    int node = blockIdx.x * 4 + (threadIdx.x >> 6);
    if (node >= n) return;
    int lane = threadIdx.x & 63;
    int off = offsets[node];
    int d   = degr_i[node];
    float ax = 0.f, ay = 0.f, sw = 0.f;
    for (int i = 0; i < d; ++i) {
        int s = csr_src[off + i];                 // broadcast load (uniform in wave)
        float w = inv_s[s];
        float2 v = *(const float2*)(nodes + (size_t)s * NDIM + lane * 2);
        ax = fmaf(w, v.x, ax);
        ay = fmaf(w, v.y, ay);
        sw += w;
    }
    float ir = inv_r[node];
    *(float2*)(out + (size_t)node * NDIM + lane * 2) = make_float2(ax * ir, ay * ir);
    if (lane == 0) swb[node] = sw * ir;
}

// ---- in-place GEMM on d_out: row = row @ W + swb[row] * b ----
// Block: 256 threads = 8 rows x 32 col-groups (4 cols each). W staged in LDS (64 KiB).
__global__ __launch_bounds__(256) void gemm_kernel(const float* __restrict__ W,
                                                   const float* __restrict__ b,
                                                   const float* __restrict__ swb,
                                                   float* __restrict__ out, int n)
{
    __shared__ __align__(16) float4 Wl[NDIM * 32];   // 64 KiB
    __shared__ __align__(16) float  nl[8][NDIM];     // 4 KiB row stage
    __shared__ __align__(16) float  bl[NDIM];

    const float4* W4 = (const float4*)W;
    for (int i = threadIdx.x; i < NDIM * 32; i += 256) Wl[i] = W4[i];
    if (threadIdx.x < NDIM) bl[threadIdx.x] = b[threadIdx.x];

    int row0 = blockIdx.x * 8;
    {
        int t  = threadIdx.x;
        int rr = t >> 5, c4 = t & 31;
        int row = row0 + rr;
        float4 v = make_float4(0.f, 0.f, 0.f, 0.f);
        if (row < n) v = *(const float4*)(out + (size_t)row * NDIM + c4 * 4);
        *(float4*)(&nl[rr][c4 * 4]) = v;
    }
    __syncthreads();

    int ty = threadIdx.x >> 5;
    int tx = threadIdx.x & 31;
    int row = row0 + ty;
    if (row >= n) return;

    float sb = swb[row];
    float4 bb = *(const float4*)(&bl[tx * 4]);
    float4 acc = make_float4(sb * bb.x, sb * bb.y, sb * bb.z, sb * bb.w);
    #pragma unroll 8
    for (int k = 0; k < NDIM; ++k) {
        float  nv = nl[ty][k];
        float4 w  = Wl[k * 32 + tx];
        acc.x = fmaf(nv, w.x, acc.x);
        acc.y = fmaf(nv, w.y, acc.y);
        acc.z = fmaf(nv, w.z, acc.z);
        acc.w = fmaf(nv, w.w, acc.w);
    }
    *(float4*)(out + (size_t)row * NDIM + tx * 4) = acc;
}

extern "C" void kernel_launch(void* const* d_in, const int* in_sizes, int n_in,
                              void* d_out, int out_size, void* d_ws, size_t ws_size,
                              hipStream_t stream)
{
    const float* nodes     = (const float*)d_in[0];
    const int*   senders   = (const int*)d_in[1];
    const int*   receivers = (const int*)d_in[2];
    const float* W         = (const float*)d_in[3];
    const float* b         = (const float*)d_in[4];
    float*       out       = (float*)d_out;

    int n  = in_sizes[0] / NDIM;   // 50000
    int ne = in_sizes[1];          // 600000
    int nb = (n + 255) / 256;      // 196 scan blocks

    // ws layout (all 4-byte elems):
    // [degs_i n | degr_i n | inv_s n | inv_r n | offsets n | cursor n | swb n | partials 256 | csr_src ne]
    int*   degs_i   = (int*)d_ws;
    int*   degr_i   = degs_i + n;
    float* inv_s    = (float*)(degr_i + n);
    float* inv_r    = inv_s + n;
    int*   offsets  = (int*)(inv_r + n);
    int*   cursor   = offsets + n;
    float* swb      = (float*)(cursor + n);
    int*   partials = (int*)(swb + n);
    int*   csr_src  = partials + 256;

    hipMemsetAsync(degs_i, 0, (size_t)2 * n * sizeof(int), stream);

    int eb = (ne + 255) / 256;
    deg_kernel<<<eb, 256, 0, stream>>>(senders, receivers, degs_i, degr_i, ne);
    invdeg_kernel<<<nb, 256, 0, stream>>>(degs_i, degr_i, inv_s, inv_r, n);
    scanA_kernel<<<nb, 256, 0, stream>>>(degr_i, partials, n);
    scanB_kernel<<<1, 256, 0, stream>>>(partials, nb);
    scanC_kernel<<<nb, 256, 0, stream>>>(degr_i, partials, offsets, cursor, n);
    fill_kernel<<<eb, 256, 0, stream>>>(senders, receivers, cursor, csr_src, ne);
    gather_kernel<<<(n + 3) / 4, 256, 0, stream>>>(nodes, csr_src, offsets, degr_i,
                                                   inv_s, inv_r, out, swb, n);
    gemm_kernel<<<(n + 7) / 8, 256, 0, stream>>>(W, b, swb, out, n);
}

// Round 3
// 183.244 us; speedup vs baseline: 6.3865x; 1.4378x over previous
//
#include <hip/hip_runtime.h>

#define NDIM 128

// ---- int degree histogram ----
__global__ __launch_bounds__(256) void deg_kernel(const int* __restrict__ senders,
                                                  const int* __restrict__ receivers,
                                                  int* __restrict__ degs_i,
                                                  int* __restrict__ degr_i, int ne)
{
    int e = blockIdx.x * 256 + threadIdx.x;
    if (e < ne) {
        atomicAdd(&degs_i[senders[e]], 1);
        atomicAdd(&degr_i[receivers[e]], 1);
    }
}

// ---- scan phase A: per-block (256) reduce of degr_i -> partials ----
__global__ __launch_bounds__(256) void scanA_kernel(const int* __restrict__ degr_i,
                                                    int* __restrict__ partials, int n)
{
    __shared__ int s[256];
    int t = threadIdx.x;
    int i = blockIdx.x * 256 + t;
    s[t] = (i < n) ? degr_i[i] : 0;
    __syncthreads();
    for (int o = 128; o > 0; o >>= 1) {
        if (t < o) s[t] += s[t + o];
        __syncthreads();
    }
    if (t == 0) partials[blockIdx.x] = s[0];
}

// ---- scan phase B: single-block exclusive scan of partials (nb <= 256) ----
__global__ __launch_bounds__(256) void scanB_kernel(int* __restrict__ partials, int nb)
{
    __shared__ int s[256];
    int t = threadIdx.x;
    int v = (t < nb) ? partials[t] : 0;
    s[t] = v;
    __syncthreads();
    for (int o = 1; o < 256; o <<= 1) {
        int add = (t >= o) ? s[t - o] : 0;
        __syncthreads();
        s[t] += add;
        __syncthreads();
    }
    if (t < nb) partials[t] = s[t] - v;   // exclusive
}

// ---- scan phase C: per-block exclusive scan + block offset -> offsets, cursor ----
__global__ __launch_bounds__(256) void scanC_kernel(const int* __restrict__ degr_i,
                                                    const int* __restrict__ partials,
                                                    int* __restrict__ offsets,
                                                    int* __restrict__ cursor, int n)
{
    __shared__ int s[256];
    int t = threadIdx.x;
    int i = blockIdx.x * 256 + t;
    int v = (i < n) ? degr_i[i] : 0;
    s[t] = v;
    __syncthreads();
    for (int o = 1; o < 256; o <<= 1) {
        int add = (t >= o) ? s[t - o] : 0;
        __syncthreads();
        s[t] += add;
        __syncthreads();
    }
    if (i < n) {
        int off = partials[blockIdx.x] + s[t] - v;
        offsets[i] = off;
        cursor[i]  = off;
    }
}

// ---- bucket fill: csr_src[pos in receiver bucket] = sender ----
__global__ __launch_bounds__(256) void fill_kernel(const int* __restrict__ senders,
                                                   const int* __restrict__ receivers,
                                                   int* __restrict__ cursor,
                                                   int* __restrict__ csr_src, int ne)
{
    int e = blockIdx.x * 256 + threadIdx.x;
    if (e < ne) {
        int r = receivers[e];
        int pos = atomicAdd(&cursor[r], 1);
        csr_src[pos] = senders[e];
    }
}

// ---- wave-per-node gather-accumulate, unrolled x4 for memory-level parallelism ----
// out_row[r] = inv_r * sum_e inv_s[s_e] * nodes[s_e];  swb[r] = inv_r * sum_e inv_s[s_e]
__global__ __launch_bounds__(256) void gather_kernel(const float* __restrict__ nodes,
                                                     const int* __restrict__ csr_src,
                                                     const int* __restrict__ offsets,
                                                     const int* __restrict__ degs_i,
                                                     const int* __restrict__ degr_i,
                                                     float* __restrict__ out,
                                                     float* __restrict__ swb, int n)
{
    int node = blockIdx.x * 4 + (threadIdx.x >> 6);
    if (node >= n) return;
    int lane = threadIdx.x & 63;
    int off = offsets[node];
    int d   = degr_i[node];
    const float* nb = nodes + (size_t)lane * 2;
    float ax = 0.f, ay = 0.f, sw = 0.f;
    int i = 0;
    for (; i + 4 <= d; i += 4) {
        // 4 independent index loads (typically one cache line)
        int s0 = csr_src[off + i + 0];
        int s1 = csr_src[off + i + 1];
        int s2 = csr_src[off + i + 2];
        int s3 = csr_src[off + i + 3];
        // 4 independent degree loads in flight
        float d0 = (float)degs_i[s0];
        float d1 = (float)degs_i[s1];
        float d2 = (float)degs_i[s2];
        float d3 = (float)degs_i[s3];
        // 4 independent row loads in flight
        float2 v0 = *(const float2*)(nb + (size_t)s0 * NDIM);
        float2 v1 = *(const float2*)(nb + (size_t)s1 * NDIM);
        float2 v2 = *(const float2*)(nb + (size_t)s2 * NDIM);
        float2 v3 = *(const float2*)(nb + (size_t)s3 * NDIM);
        float w0 = rsqrtf(fmaxf(d0, 1.0f));
        float w1 = rsqrtf(fmaxf(d1, 1.0f));
        float w2 = rsqrtf(fmaxf(d2, 1.0f));
        float w3 = rsqrtf(fmaxf(d3, 1.0f));
        ax = fmaf(w0, v0.x, ax); ay = fmaf(w0, v0.y, ay);
        ax = fmaf(w1, v1.x, ax); ay = fmaf(w1, v1.y, ay);
        ax = fmaf(w2, v2.x, ax); ay = fmaf(w2, v2.y, ay);
        ax = fmaf(w3, v3.x, ax); ay = fmaf(w3, v3.y, ay);
        sw += w0 + w1 + w2 + w3;
    }
    for (; i < d; ++i) {
        int s = csr_src[off + i];
        float w = rsqrtf(fmaxf((float)degs_i[s], 1.0f));
        float2 v = *(const float2*)(nb + (size_t)s * NDIM);
        ax = fmaf(w, v.x, ax);
        ay = fmaf(w, v.y, ay);
        sw += w;
    }
    float ir = rsqrtf(fmaxf((float)degr_i[node], 1.0f));
    *(float2*)(out + (size_t)node * NDIM + lane * 2) = make_float2(ax * ir, ay * ir);
    if (lane == 0) swb[node] = sw * ir;
}

// ---- in-place GEMM on d_out: row = row @ W + swb[row] * b ----
// Block: 256 threads, 32 rows x 128 cols. Each thread: 4 rows x 4 cols micro-tile.
// Transposed row stage nlT[k][row] -> per k: 2x ds_read_b128 for 16 FMA (VALU-bound).
__global__ __launch_bounds__(256) void gemm_kernel(const float* __restrict__ W,
                                                   const float* __restrict__ b,
                                                   const float* __restrict__ swb,
                                                   float* __restrict__ out, int n)
{
    __shared__ __align__(16) float4 Wl[NDIM * 32];    // 64 KiB: W[k][c4]
    __shared__ __align__(16) float  nlT[NDIM][32];    // 16 KiB: row-block transposed

    const float4* W4 = (const float4*)W;
    for (int i = threadIdx.x; i < NDIM * 32; i += 256) Wl[i] = W4[i];

    int row0 = blockIdx.x * 32;
    {
        int r  = threadIdx.x & 31;          // row within block
        int c8 = threadIdx.x >> 5;          // 0..7
        int row = row0 + r;
        #pragma unroll
        for (int j = 0; j < 4; ++j) {
            int cc = c8 + j * 8;            // col4 index 0..31
            float4 v = make_float4(0.f, 0.f, 0.f, 0.f);
            if (row < n) v = *(const float4*)(out + (size_t)row * NDIM + cc * 4);
            nlT[cc * 4 + 0][r] = v.x;
            nlT[cc * 4 + 1][r] = v.y;
            nlT[cc * 4 + 2][r] = v.z;
            nlT[cc * 4 + 3][r] = v.w;
        }
    }
    __syncthreads();

    int tx = threadIdx.x & 31;   // col4 group
    int ty = threadIdx.x >> 5;   // row group 0..7 -> rows ty*4..ty*4+3
    int r0 = row0 + ty * 4;

    float4 bb = *(const float4*)(b + tx * 4);
    float sb0 = (r0 + 0 < n) ? swb[r0 + 0] : 0.f;
    float sb1 = (r0 + 1 < n) ? swb[r0 + 1] : 0.f;
    float sb2 = (r0 + 2 < n) ? swb[r0 + 2] : 0.f;
    float sb3 = (r0 + 3 < n) ? swb[r0 + 3] : 0.f;
    float4 acc0 = make_float4(sb0 * bb.x, sb0 * bb.y, sb0 * bb.z, sb0 * bb.w);
    float4 acc1 = make_float4(sb1 * bb.x, sb1 * bb.y, sb1 * bb.z, sb1 * bb.w);
    float4 acc2 = make_float4(sb2 * bb.x, sb2 * bb.y, sb2 * bb.z, sb2 * bb.w);
    float4 acc3 = make_float4(sb3 * bb.x, sb3 * bb.y, sb3 * bb.z, sb3 * bb.w);

    #pragma unroll 8
    for (int k = 0; k < NDIM; ++k) {
        float4 a = *(const float4*)(&nlT[k][ty * 4]);
        float4 w = Wl[k * 32 + tx];
        acc0.x = fmaf(a.x, w.x, acc0.x); acc0.y = fmaf(a.x, w.y, acc0.y);
        acc0.z = fmaf(a.x, w.z, acc0.z); acc0.w = fmaf(a.x, w.w, acc0.w);
        acc1.x = fmaf(a.y, w.x, acc1.x); acc1.y = fmaf(a.y, w.y, acc1.y);
        acc1.z = fmaf(a.y, w.z, acc1.z); acc1.w = fmaf(a.y, w.w, acc1.w);
        acc2.x = fmaf(a.z, w.x, acc2.x); acc2.y = fmaf(a.z, w.y, acc2.y);
        acc2.z = fmaf(a.z, w.z, acc2.z); acc2.w = fmaf(a.z, w.w, acc2.w);
        acc3.x = fmaf(a.w, w.x, acc3.x); acc3.y = fmaf(a.w, w.y, acc3.y);
        acc3.z = fmaf(a.w, w.z, acc3.z); acc3.w = fmaf(a.w, w.w, acc3.w);
    }

    if (r0 + 0 < n) *(float4*)(out + (size_t)(r0 + 0) * NDIM + tx * 4) = acc0;
    if (r0 + 1 < n) *(float4*)(out + (size_t)(r0 + 1) * NDIM + tx * 4) = acc1;
    if (r0 + 2 < n) *(float4*)(out + (size_t)(r0 + 2) * NDIM + tx * 4) = acc2;
    if (r0 + 3 < n) *(float4*)(out + (size_t)(r0 + 3) * NDIM + tx * 4) = acc3;
}

extern "C" void kernel_launch(void* const* d_in, const int* in_sizes, int n_in,
                              void* d_out, int out_size, void* d_ws, size_t ws_size,
                              hipStream_t stream)
{
    const float* nodes     = (const float*)d_in[0];
    const int*   senders   = (const int*)d_in[1];
    const int*   receivers = (const int*)d_in[2];
    const float* W         = (const float*)d_in[3];
    const float* b         = (const float*)d_in[4];
    float*       out       = (float*)d_out;

    int n  = in_sizes[0] / NDIM;   // 50000
    int ne = in_sizes[1];          // 600000
    int nb = (n + 255) / 256;      // 196 scan blocks

    // ws layout: [degs_i n | degr_i n | offsets n | cursor n | swb n | partials 256 | csr_src ne]
    int*   degs_i   = (int*)d_ws;
    int*   degr_i   = degs_i + n;
    int*   offsets  = degr_i + n;
    int*   cursor   = offsets + n;
    float* swb      = (float*)(cursor + n);
    int*   partials = (int*)(swb + n);
    int*   csr_src  = partials + 256;

    hipMemsetAsync(degs_i, 0, (size_t)2 * n * sizeof(int), stream);

    int eb = (ne + 255) / 256;
    deg_kernel<<<eb, 256, 0, stream>>>(senders, receivers, degs_i, degr_i, ne);
    scanA_kernel<<<nb, 256, 0, stream>>>(degr_i, partials, n);
    scanB_kernel<<<1, 256, 0, stream>>>(partials, nb);
    scanC_kernel<<<nb, 256, 0, stream>>>(degr_i, partials, offsets, cursor, n);
    fill_kernel<<<eb, 256, 0, stream>>>(senders, receivers, cursor, csr_src, ne);
    gather_kernel<<<(n + 3) / 4, 256, 0, stream>>>(nodes, csr_src, offsets,
                                                   degs_i, degr_i, out, swb, n);
    gemm_kernel<<<(n + 31) / 32, 256, 0, stream>>>(W, b, swb, out, n);
}